// Round 8
// baseline (521.036 us; speedup 1.0000x reference)
//
#include <hip/hip_runtime.h>
#include <math.h>

#define NN 50000
#define NE 400000
#define DDIM 128
#define NHEAD 4
#define NRAD 50
#define NGRAPH 100
#define TEMB 32
#define DOUT 512
#define CUTF 6.0f
#define PI_F 3.14159265358979323846f

#define SCAN_N ((NN + 255) / 256)  // 196 scan blocks

typedef unsigned int uint;
typedef unsigned short ushort;
typedef __attribute__((ext_vector_type(8))) short short8;
typedef __attribute__((ext_vector_type(4))) float f32x4;

// ---------------- helpers ----------------

__device__ __forceinline__ float gelu_tanh(float v) {
  float u = 0.7978845608028654f * (v + 0.044715f * v * v * v);
  return 0.5f * v * (1.0f + tanhf(u));
}

__device__ __forceinline__ ushort f2bf(float f) {  // RNE
  uint u = __float_as_uint(f);
  uint r = (u + 0x7fffu + ((u >> 16) & 1u)) >> 16;
  return (ushort)r;
}
__device__ __forceinline__ float bfl(uint u) { return __uint_as_float(u << 16); }
__device__ __forceinline__ float bfh(uint u) { return __uint_as_float(u & 0xffff0000u); }

__global__ void k_fill_f(float* p, float v, int n) {
  int i = blockIdx.x * blockDim.x + threadIdx.x;
  if (i < n) p[i] = v;
}
__global__ void k_fill_i(int* p, int v, int n) {
  int i = blockIdx.x * blockDim.x + threadIdx.x;
  if (i < n) p[i] = v;
}

// ---------------- weight pre-convert + transpose: Wtb[l][fam][c][k] bf16 ----------------

__global__ void k_wconv(const float* __restrict__ Wq, const float* __restrict__ Wk,
                        const float* __restrict__ Wv, const float* __restrict__ Wo,
                        const float* __restrict__ Wm1, const float* __restrict__ Wm2,
                        ushort* __restrict__ Wtb) {
  int idx = blockIdx.x * 256 + threadIdx.x;  // 12*16384
  int m = idx >> 14;
  int r = idx & 16383;
  int c = r >> 7, k = r & 127;
  int l = m / 6, fam = m % 6;
  const float* src = fam == 0 ? Wq : fam == 1 ? Wk : fam == 2 ? Wv
                   : fam == 3 ? Wo : fam == 4 ? Wm1 : Wm2;
  Wtb[idx] = f2bf(src[l * 16384 + k * 128 + c]);
}

// ---------------- init: x = [emb[at], pos] @ W_init + b ----------------

__global__ void k_init(const float* __restrict__ pos, const int* __restrict__ at,
                       const float* __restrict__ emb, const float* __restrict__ W,
                       const float* __restrict__ b, float* __restrict__ x) {
  int idx = blockIdx.x * blockDim.x + threadIdx.x;
  if (idx >= NN * DDIM) return;
  int n = idx >> 7, c = idx & 127;
  const float* er = emb + (size_t)at[n] * TEMB;
  float acc = b[c];
#pragma unroll
  for (int t = 0; t < TEMB; ++t) acc = fmaf(er[t], W[t * DDIM + c], acc);
  acc = fmaf(pos[n * 3 + 0], W[(TEMB + 0) * DDIM + c], acc);
  acc = fmaf(pos[n * 3 + 1], W[(TEMB + 1) * DDIM + c], acc);
  acc = fmaf(pos[n * 3 + 2], W[(TEMB + 2) * DDIM + c], acc);
  x[idx] = acc;
}

// ---------------- per-edge distance + degree histogram (fused) ----------------

__global__ void k_edge(const float* __restrict__ pos, const int* __restrict__ ei,
                       float* __restrict__ de, int* __restrict__ deg) {
  int e = blockIdx.x * blockDim.x + threadIdx.x;
  if (e >= NE) return;
  int s = ei[e], t = ei[NE + e];
  float dx = pos[s * 3 + 0] - pos[t * 3 + 0] + 1e-8f;
  float dy = pos[s * 3 + 1] - pos[t * 3 + 1] + 1e-8f;
  float dz = pos[s * 3 + 2] - pos[t * 3 + 2] + 1e-8f;
  de[e] = sqrtf(dx * dx + dy * dy + dz * dz);
  atomicAdd(&deg[t], 1);
}

// ---------------- CSR build: parallel 3-pass exclusive scan ----------------

__global__ void k_scan1(const int* __restrict__ deg, int* __restrict__ bsum) {
  __shared__ int red[256];
  int i = blockIdx.x * 256 + threadIdx.x;
  red[threadIdx.x] = (i < NN) ? deg[i] : 0;
  __syncthreads();
  for (int off = 128; off > 0; off >>= 1) {
    if (threadIdx.x < off) red[threadIdx.x] += red[threadIdx.x + off];
    __syncthreads();
  }
  if (threadIdx.x == 0) bsum[blockIdx.x] = red[0];
}

__global__ void k_scan2(int* __restrict__ bsum) {  // 1 block, 256 threads >= SCAN_N
  __shared__ int sh[256];
  int t = threadIdx.x;
  int v = (t < SCAN_N) ? bsum[t] : 0;
  sh[t] = v;
  __syncthreads();
  for (int off = 1; off < 256; off <<= 1) {
    int u = (t >= off) ? sh[t - off] : 0;
    __syncthreads();
    sh[t] += u;
    __syncthreads();
  }
  if (t < SCAN_N) bsum[t] = (t == 0) ? 0 : sh[t - 1];
}

__global__ void k_scan3(const int* __restrict__ deg, const int* __restrict__ bsum,
                        int* __restrict__ rowptr, int* __restrict__ cnear,
                        int* __restrict__ cfar) {
  __shared__ int sh[256];
  int t = threadIdx.x;
  int i = blockIdx.x * 256 + t;
  int v = (i < NN) ? deg[i] : 0;
  sh[t] = v;
  __syncthreads();
  for (int off = 1; off < 256; off <<= 1) {
    int u = (t >= off) ? sh[t - off] : 0;
    __syncthreads();
    sh[t] += u;
    __syncthreads();
  }
  int excl = bsum[blockIdx.x] + sh[t] - v;
  if (i < NN) {
    rowptr[i] = excl;
    cnear[i] = excl;
    cfar[i] = excl + v;  // = rowptr[i+1]
    if (i == NN - 1) rowptr[NN] = excl + v;
  }
}

// scatter into near-first / far-last segmented CSR, packed records {src, d}
__global__ void k_scatter(const int* __restrict__ ei, const float* __restrict__ de,
                          int* __restrict__ cnear, int* __restrict__ cfar,
                          int2* __restrict__ er) {
  int e = blockIdx.x * blockDim.x + threadIdx.x;
  if (e >= NE) return;
  int src = ei[e], dst = ei[NE + e];
  float d = de[e];
  int idx;
  if (d < CUTF)
    idx = atomicAdd(&cnear[dst], 1);
  else
    idx = atomicSub(&cfar[dst], 1) - 1;
  er[idx] = make_int2(src, __float_as_int(d));
}

// ---------------- fused QKV GEMM: stage x once, 3 weights ----------------
// block 256 = 4 waves; 128 rows x 128 cols; 16x16x32 bf16 MFMA; wave owns 32 rows.

__global__ __launch_bounds__(256) void k_qkv(
    const float* __restrict__ x, const ushort* __restrict__ Wt3,
    ushort* __restrict__ qo, ushort* __restrict__ ko, ushort* __restrict__ vo) {
  __shared__ ushort Al[128 * 128];
  __shared__ ushort Wl[128 * 128];
  const int tid = threadIdx.x;
  const int r0 = blockIdx.x * 128;

  for (int i = tid; i < 128 * 16; i += 256) {
    int r = i >> 4, g = i & 15;
    int gr = r0 + r;
    float4 f0 = {0, 0, 0, 0}, f1 = {0, 0, 0, 0};
    if (gr < NN) {
      f0 = *(const float4*)&x[(size_t)gr * 128 + g * 8];
      f1 = *(const float4*)&x[(size_t)gr * 128 + g * 8 + 4];
    }
    int gs = g ^ (r & 7);
    ushort4 u0 = {f2bf(f0.x), f2bf(f0.y), f2bf(f0.z), f2bf(f0.w)};
    ushort4 u1 = {f2bf(f1.x), f2bf(f1.y), f2bf(f1.z), f2bf(f1.w)};
    *(ushort4*)&Al[r * 128 + gs * 8] = u0;
    *(ushort4*)&Al[r * 128 + gs * 8 + 4] = u1;
  }

  const int w = tid >> 6, l = tid & 63;
  const int lg = l >> 4, lr = l & 15;

  for (int m = 0; m < 3; ++m) {
    for (int i = tid; i < 128 * 16; i += 256) {
      int c = i >> 4, g = i & 15;
      ushort4 w0 = *(const ushort4*)&Wt3[m * 16384 + c * 128 + g * 8];
      ushort4 w1 = *(const ushort4*)&Wt3[m * 16384 + c * 128 + g * 8 + 4];
      int gs = g ^ (c & 7);
      *(ushort4*)&Wl[c * 128 + gs * 8] = w0;
      *(ushort4*)&Wl[c * 128 + gs * 8 + 4] = w1;
    }
    __syncthreads();

    f32x4 acc[2][8];
#pragma unroll
    for (int rt = 0; rt < 2; ++rt)
#pragma unroll
      for (int ct = 0; ct < 8; ++ct) acc[rt][ct] = (f32x4){0.f, 0.f, 0.f, 0.f};

#pragma unroll
    for (int ks = 0; ks < 4; ++ks) {
      short8 af[2];
#pragma unroll
      for (int rt = 0; rt < 2; ++rt) {
        int arow = w * 32 + rt * 16 + lr;
        int ga = (ks * 4 + lg) ^ (arow & 7);
        af[rt] = *(const short8*)&Al[arow * 128 + ga * 8];
      }
#pragma unroll
      for (int ct = 0; ct < 8; ++ct) {
        int col = ct * 16 + lr;
        int gb = (ks * 4 + lg) ^ (col & 7);
        short8 bf = *(const short8*)&Wl[col * 128 + gb * 8];
#pragma unroll
        for (int rt = 0; rt < 2; ++rt)
          acc[rt][ct] = __builtin_amdgcn_mfma_f32_16x16x32_bf16(af[rt], bf, acc[rt][ct], 0, 0, 0);
      }
    }

    ushort* o = (m == 0) ? qo : (m == 1) ? ko : vo;
#pragma unroll
    for (int rt = 0; rt < 2; ++rt)
#pragma unroll
      for (int ct = 0; ct < 8; ++ct) {
        int col = ct * 16 + lr;
#pragma unroll
        for (int r = 0; r < 4; ++r) {
          int row = r0 + w * 32 + rt * 16 + lg * 4 + r;
          if (row < NN) o[(size_t)row * 128 + col] = f2bf(acc[rt][ct][r]);
        }
      }
    __syncthreads();
  }
}

// ---------------- megafused FC tail: x += msg@Wo; hb=LN(x); h2=gelu(hb@Wm1+bm1);
// ---------------- x += h2@Wm2 + bm2 — one kernel, one pass over node data.
// Wt points at [Wo^T | Wm1^T | Wm2^T] (fam 3..5 of the layer, each 16384 bf16).

__global__ __launch_bounds__(256) void k_fc(
    const ushort* __restrict__ msgb, const ushort* __restrict__ Wt,
    float* __restrict__ x, const float* __restrict__ lng,
    const float* __restrict__ lnb, const float* __restrict__ bm1,
    const float* __restrict__ bm2) {
  __shared__ ushort Al[128 * 128];
  __shared__ ushort Wl[128 * 128];
  const int tid = threadIdx.x;
  const int r0 = blockIdx.x * 128;
  const int w = tid >> 6, l = tid & 63;
  const int lg = l >> 4, lr = l & 15;

  // ---- stage A <- msg, W <- Wo ----
  for (int i = tid; i < 128 * 16; i += 256) {
    int r = i >> 4, g = i & 15;
    int gr = r0 + r;
    ushort4 v0 = {0, 0, 0, 0}, v1 = {0, 0, 0, 0};
    if (gr < NN) {
      v0 = *(const ushort4*)&msgb[(size_t)gr * 128 + g * 8];
      v1 = *(const ushort4*)&msgb[(size_t)gr * 128 + g * 8 + 4];
    }
    int gs = g ^ (r & 7);
    *(ushort4*)&Al[r * 128 + gs * 8] = v0;
    *(ushort4*)&Al[r * 128 + gs * 8 + 4] = v1;
  }
  for (int i = tid; i < 128 * 16; i += 256) {
    int c = i >> 4, g = i & 15;
    ushort4 w0 = *(const ushort4*)&Wt[c * 128 + g * 8];
    ushort4 w1 = *(const ushort4*)&Wt[c * 128 + g * 8 + 4];
    int gs = g ^ (c & 7);
    *(ushort4*)&Wl[c * 128 + gs * 8] = w0;
    *(ushort4*)&Wl[c * 128 + gs * 8 + 4] = w1;
  }
  __syncthreads();

  // ---- GEMM1: t1 = msg@Wo + x ----
  f32x4 t1[2][8];
#pragma unroll
  for (int rt = 0; rt < 2; ++rt)
#pragma unroll
    for (int ct = 0; ct < 8; ++ct) t1[rt][ct] = (f32x4){0.f, 0.f, 0.f, 0.f};
#pragma unroll
  for (int ks = 0; ks < 4; ++ks) {
    short8 af[2];
#pragma unroll
    for (int rt = 0; rt < 2; ++rt) {
      int arow = w * 32 + rt * 16 + lr;
      int ga = (ks * 4 + lg) ^ (arow & 7);
      af[rt] = *(const short8*)&Al[arow * 128 + ga * 8];
    }
#pragma unroll
    for (int ct = 0; ct < 8; ++ct) {
      int col = ct * 16 + lr;
      int gb = (ks * 4 + lg) ^ (col & 7);
      short8 bf = *(const short8*)&Wl[col * 128 + gb * 8];
#pragma unroll
      for (int rt = 0; rt < 2; ++rt)
        t1[rt][ct] = __builtin_amdgcn_mfma_f32_16x16x32_bf16(af[rt], bf, t1[rt][ct], 0, 0, 0);
    }
  }
  // add residual x
#pragma unroll
  for (int rt = 0; rt < 2; ++rt)
#pragma unroll
    for (int r = 0; r < 4; ++r) {
      int row = r0 + w * 32 + rt * 16 + lg * 4 + r;
      if (row < NN)
#pragma unroll
        for (int ct = 0; ct < 8; ++ct)
          t1[rt][ct][r] += x[(size_t)row * 128 + ct * 16 + lr];
    }
  __syncthreads();  // all reads of Al/Wl done

  // ---- LN per row -> hb (bf16) into Al ----
#pragma unroll
  for (int rt = 0; rt < 2; ++rt)
#pragma unroll
    for (int r = 0; r < 4; ++r) {
      int rl = w * 32 + rt * 16 + lg * 4 + r;
      float s = 0.f, ss = 0.f;
#pragma unroll
      for (int ct = 0; ct < 8; ++ct) {
        float v = t1[rt][ct][r];
        s += v;
        ss = fmaf(v, v, ss);
      }
#pragma unroll
      for (int msk = 8; msk >= 1; msk >>= 1) {
        s += __shfl_xor(s, msk);
        ss += __shfl_xor(ss, msk);
      }
      float mean = s * (1.0f / DDIM);
      float var = ss * (1.0f / DDIM) - mean * mean;
      float inv = rsqrtf(var + 1e-5f);
#pragma unroll
      for (int ct = 0; ct < 8; ++ct) {
        int col = ct * 16 + lr;
        int g = col >> 3;
        int gs = g ^ (rl & 7);
        Al[rl * 128 + gs * 8 + (col & 7)] =
            f2bf((t1[rt][ct][r] - mean) * inv * lng[col] + lnb[col]);
      }
    }
  // stage W <- Wm1
  for (int i = tid; i < 128 * 16; i += 256) {
    int c = i >> 4, g = i & 15;
    ushort4 w0 = *(const ushort4*)&Wt[16384 + c * 128 + g * 8];
    ushort4 w1 = *(const ushort4*)&Wt[16384 + c * 128 + g * 8 + 4];
    int gs = g ^ (c & 7);
    *(ushort4*)&Wl[c * 128 + gs * 8] = w0;
    *(ushort4*)&Wl[c * 128 + gs * 8 + 4] = w1;
  }
  __syncthreads();

  // ---- GEMM2: acc = hb@Wm1 ----
  f32x4 acc[2][8];
#pragma unroll
  for (int rt = 0; rt < 2; ++rt)
#pragma unroll
    for (int ct = 0; ct < 8; ++ct) acc[rt][ct] = (f32x4){0.f, 0.f, 0.f, 0.f};
#pragma unroll
  for (int ks = 0; ks < 4; ++ks) {
    short8 af[2];
#pragma unroll
    for (int rt = 0; rt < 2; ++rt) {
      int arow = w * 32 + rt * 16 + lr;
      int ga = (ks * 4 + lg) ^ (arow & 7);
      af[rt] = *(const short8*)&Al[arow * 128 + ga * 8];
    }
#pragma unroll
    for (int ct = 0; ct < 8; ++ct) {
      int col = ct * 16 + lr;
      int gb = (ks * 4 + lg) ^ (col & 7);
      short8 bf = *(const short8*)&Wl[col * 128 + gb * 8];
#pragma unroll
      for (int rt = 0; rt < 2; ++rt)
        acc[rt][ct] = __builtin_amdgcn_mfma_f32_16x16x32_bf16(af[rt], bf, acc[rt][ct], 0, 0, 0);
    }
  }
  __syncthreads();  // all reads of Al (hb) done

  // ---- gelu + bm1 -> h2 (bf16) into Al ----
#pragma unroll
  for (int rt = 0; rt < 2; ++rt)
#pragma unroll
    for (int r = 0; r < 4; ++r) {
      int rl = w * 32 + rt * 16 + lg * 4 + r;
#pragma unroll
      for (int ct = 0; ct < 8; ++ct) {
        int col = ct * 16 + lr;
        float v = gelu_tanh(acc[rt][ct][r] + bm1[col]);
        int g = col >> 3;
        int gs = g ^ (rl & 7);
        Al[rl * 128 + gs * 8 + (col & 7)] = f2bf(v);
      }
    }
  // stage W <- Wm2
  for (int i = tid; i < 128 * 16; i += 256) {
    int c = i >> 4, g = i & 15;
    ushort4 w0 = *(const ushort4*)&Wt[2 * 16384 + c * 128 + g * 8];
    ushort4 w1 = *(const ushort4*)&Wt[2 * 16384 + c * 128 + g * 8 + 4];
    int gs = g ^ (c & 7);
    *(ushort4*)&Wl[c * 128 + gs * 8] = w0;
    *(ushort4*)&Wl[c * 128 + gs * 8 + 4] = w1;
  }
  __syncthreads();

  // ---- GEMM3: acc = h2@Wm2; x = t1 + acc + bm2 ----
#pragma unroll
  for (int rt = 0; rt < 2; ++rt)
#pragma unroll
    for (int ct = 0; ct < 8; ++ct) acc[rt][ct] = (f32x4){0.f, 0.f, 0.f, 0.f};
#pragma unroll
  for (int ks = 0; ks < 4; ++ks) {
    short8 af[2];
#pragma unroll
    for (int rt = 0; rt < 2; ++rt) {
      int arow = w * 32 + rt * 16 + lr;
      int ga = (ks * 4 + lg) ^ (arow & 7);
      af[rt] = *(const short8*)&Al[arow * 128 + ga * 8];
    }
#pragma unroll
    for (int ct = 0; ct < 8; ++ct) {
      int col = ct * 16 + lr;
      int gb = (ks * 4 + lg) ^ (col & 7);
      short8 bf = *(const short8*)&Wl[col * 128 + gb * 8];
#pragma unroll
      for (int rt = 0; rt < 2; ++rt)
        acc[rt][ct] = __builtin_amdgcn_mfma_f32_16x16x32_bf16(af[rt], bf, acc[rt][ct], 0, 0, 0);
    }
  }
#pragma unroll
  for (int rt = 0; rt < 2; ++rt)
#pragma unroll
    for (int r = 0; r < 4; ++r) {
      int row = r0 + w * 32 + rt * 16 + lg * 4 + r;
      if (row < NN)
#pragma unroll
        for (int ct = 0; ct < 8; ++ct) {
          int col = ct * 16 + lr;
          x[(size_t)row * 128 + col] = t1[rt][ct][r] + acc[rt][ct][r] + bm2[col];
        }
    }
}

// ---------------- qe precompute: qe[n][j][h] ----------------

__global__ __launch_bounds__(256) void k_qe(const ushort* __restrict__ qnb,
                                            const float* __restrict__ We,
                                            ushort* __restrict__ qe) {
  __shared__ float Wlds[NRAD][DDIM + 1];
  __shared__ float qlds[4][DDIM];
  int tid = threadIdx.x;
  for (int i = tid; i < NRAD * DDIM; i += 256) Wlds[i / DDIM][i % DDIM] = We[i];
  __syncthreads();
  int w = tid >> 6, t = tid & 63;
  for (int rep = 0; rep < 2; ++rep) {
    int n = blockIdx.x * 8 + rep * 4 + w;
    uint qu = *(const uint*)&qnb[(size_t)n * DDIM + 2 * t];
    qlds[w][2 * t] = bfl(qu);
    qlds[w][2 * t + 1] = bfh(qu);
    if (t < NRAD) {
      float e0 = 0.f, e1 = 0.f, e2 = 0.f, e3 = 0.f;
#pragma unroll
      for (int d = 0; d < 32; ++d) e0 = fmaf(Wlds[t][d], qlds[w][d], e0);
#pragma unroll
      for (int d = 32; d < 64; ++d) e1 = fmaf(Wlds[t][d], qlds[w][d], e1);
#pragma unroll
      for (int d = 64; d < 96; ++d) e2 = fmaf(Wlds[t][d], qlds[w][d], e2);
#pragma unroll
      for (int d = 96; d < 128; ++d) e3 = fmaf(Wlds[t][d], qlds[w][d], e3);
      ushort4 o = {f2bf(e0), f2bf(e1), f2bf(e2), f2bf(e3)};
      *(ushort4*)&qe[(size_t)n * (NRAD * 4) + 4 * t] = o;
    }
  }
}

// ---------------- fused attention v4: near/far split CSR, butterfly softmax ----------------

__device__ __forceinline__ float rbf_fill(float d, int j) {
  const float step = CUTF / (NRAD - 1);
  const float gamma = (NRAD / CUTF) * (NRAD / CUTF);
  float mu = j * step;
  float dm = d - mu;
  float env = 0.5f * (__cosf(PI_F * d / CUTF) + 1.0f);
  return __expf(-gamma * dm * dm) * env;
}

#define SCALE_QK 0.17677669529663687f

__global__ __launch_bounds__(256) void k_attn4(
    const ushort* __restrict__ qnb, const ushort* __restrict__ knb,
    const ushort* __restrict__ vnb, const ushort* __restrict__ qe,
    const int2* __restrict__ er, const int* __restrict__ rowptr,
    const int* __restrict__ nearend, const float* __restrict__ We,
    ushort* __restrict__ msgb) {
  __shared__ float qel[4][64][4];   // [wave][j][head]; reused for arbn in epilogue
  __shared__ float rbl[4][64];
  __shared__ ushort Wel[NRAD * DDIM];
  const int tid = threadIdx.x;
  for (int i = tid; i < NRAD * DDIM; i += 256) Wel[i] = f2bf(We[i]);
  __syncthreads();

  const int w = tid >> 6, t = tid & 63;
  const int n = blockIdx.x * 4 + w;
  const int h = t >> 4;
  const int j0 = t & 15;
  uint qu = *(const uint*)&qnb[(size_t)n * DDIM + 2 * t];
  const float q0 = bfl(qu), q1 = bfh(qu);
  if (t < NRAD) {
    ushort4 qv = *(const ushort4*)&qe[(size_t)n * (NRAD * 4) + 4 * t];
    qel[w][t][0] = bfl(qv.x);
    qel[w][t][1] = bfl(qv.y);
    qel[w][t][2] = bfl(qv.z);
    qel[w][t][3] = bfl(qv.w);
  } else {
    qel[w][t][0] = 0.f; qel[w][t][1] = 0.f; qel[w][t][2] = 0.f; qel[w][t][3] = 0.f;
  }
  const int start = rowptr[n], nend = nearend[n], end = rowptr[n + 1];

  float s = 0.f, a0 = 0.f, a1 = 0.f;
  float4 arb = {0.f, 0.f, 0.f, 0.f};

  // ---- near loop (radial features active) ----
  for (int cb = start; cb < nend; cb += 64) {
    int cnt = min(nend - cb, 64);
    int2 e_t = make_int2(0, 0);
    if (t < cnt) e_t = er[cb + t];
    for (int i = 0; i < cnt; ++i) {
      int src = __shfl(e_t.x, i);
      float dd = __shfl(__int_as_float(e_t.y), i);
      uint ku = *(const uint*)&knb[(size_t)src * DDIM + 2 * t];
      uint vu = *(const uint*)&vnb[(size_t)src * DDIM + 2 * t];
      float pr = q0 * bfl(ku) + q1 * bfh(ku);
      float rb = (t < NRAD) ? rbf_fill(dd, t) : 0.f;
      rbl[w][t] = rb;
      pr = fmaf(rbl[w][j0], qel[w][j0][h], pr);
      pr = fmaf(rbl[w][j0 + 16], qel[w][j0 + 16][h], pr);
      pr = fmaf(rbl[w][j0 + 32], qel[w][j0 + 32][h], pr);
      pr = fmaf(rbl[w][j0 + 48], qel[w][j0 + 48][h], pr);
      pr += __shfl_xor(pr, 1);
      pr += __shfl_xor(pr, 2);
      pr += __shfl_xor(pr, 4);
      pr += __shfl_xor(pr, 8);
      float ae = __expf(fminf(pr * SCALE_QK, 60.f));
      s += ae;
      a0 = fmaf(ae, bfl(vu), a0);
      a1 = fmaf(ae, bfh(vu), a1);
      float aex = __shfl(ae, 0);
      float aey = __shfl(ae, 16);
      float aez = __shfl(ae, 32);
      float aew = __shfl(ae, 48);
      arb.x = fmaf(rb, aex, arb.x);
      arb.y = fmaf(rb, aey, arb.y);
      arb.z = fmaf(rb, aez, arb.z);
      arb.w = fmaf(rb, aew, arb.w);
    }
  }

  // ---- far loop (no radial), 2-edge unrolled for ILP ----
  float s1 = 0.f, b0 = 0.f, b1 = 0.f;
  for (int cb = nend; cb < end; cb += 64) {
    int cnt = min(end - cb, 64);
    int src_t = 0;
    if (t < cnt) src_t = er[cb + t].x;
    int i = 0;
    for (; i + 2 <= cnt; i += 2) {
      int sA = __shfl(src_t, i);
      int sB = __shfl(src_t, i + 1);
      uint kuA = *(const uint*)&knb[(size_t)sA * DDIM + 2 * t];
      uint kuB = *(const uint*)&knb[(size_t)sB * DDIM + 2 * t];
      uint vuA = *(const uint*)&vnb[(size_t)sA * DDIM + 2 * t];
      uint vuB = *(const uint*)&vnb[(size_t)sB * DDIM + 2 * t];
      float pA = q0 * bfl(kuA) + q1 * bfh(kuA);
      float pB = q0 * bfl(kuB) + q1 * bfh(kuB);
      pA += __shfl_xor(pA, 1);
      pB += __shfl_xor(pB, 1);
      pA += __shfl_xor(pA, 2);
      pB += __shfl_xor(pB, 2);
      pA += __shfl_xor(pA, 4);
      pB += __shfl_xor(pB, 4);
      pA += __shfl_xor(pA, 8);
      pB += __shfl_xor(pB, 8);
      float aeA = __expf(fminf(pA * SCALE_QK, 60.f));
      float aeB = __expf(fminf(pB * SCALE_QK, 60.f));
      s += aeA;
      s1 += aeB;
      a0 = fmaf(aeA, bfl(vuA), a0);
      b0 = fmaf(aeB, bfl(vuB), b0);
      a1 = fmaf(aeA, bfh(vuA), a1);
      b1 = fmaf(aeB, bfh(vuB), b1);
    }
    if (i < cnt) {
      int sA = __shfl(src_t, i);
      uint kuA = *(const uint*)&knb[(size_t)sA * DDIM + 2 * t];
      uint vuA = *(const uint*)&vnb[(size_t)sA * DDIM + 2 * t];
      float pA = q0 * bfl(kuA) + q1 * bfh(kuA);
      pA += __shfl_xor(pA, 1);
      pA += __shfl_xor(pA, 2);
      pA += __shfl_xor(pA, 4);
      pA += __shfl_xor(pA, 8);
      float aeA = __expf(fminf(pA * SCALE_QK, 60.f));
      s += aeA;
      a0 = fmaf(aeA, bfl(vuA), a0);
      a1 = fmaf(aeA, bfh(vuA), a1);
    }
  }
  s += s1;
  a0 += b0;
  a1 += b1;

  // ---- finalize: normalize; msg = a_norm + (arb_norm @ We) ----
  float4 s4 = {__shfl(s, 0), __shfl(s, 16), __shfl(s, 32), __shfl(s, 48)};
  float4 inv4 = {1.f / (s4.x + 1e-9f), 1.f / (s4.y + 1e-9f),
                 1.f / (s4.z + 1e-9f), 1.f / (s4.w + 1e-9f)};
  float invo = 1.f / (s + 1e-9f);
  if (t < NRAD) {
    qel[w][t][0] = arb.x * inv4.x;
    qel[w][t][1] = arb.y * inv4.y;
    qel[w][t][2] = arb.z * inv4.z;
    qel[w][t][3] = arb.w * inv4.w;
  }
  a0 *= invo;
  a1 *= invo;
#pragma unroll 10
  for (int j = 0; j < NRAD; ++j) {
    float ar = qel[w][j][h];
    uint wu = *(const uint*)&Wel[j * DDIM + 2 * t];
    a0 = fmaf(ar, bfl(wu), a0);
    a1 = fmaf(ar, bfh(wu), a1);
  }
  uint pk = (uint)f2bf(a0) | ((uint)f2bf(a1) << 16);
  *(uint*)&msgb[(size_t)n * DDIM + 2 * t] = pk;
}

// ---------------- graph sum (batch is sorted): 32 nodes/block, boundary atomics ----------------

#define GS_NODES 32
__global__ void k_graphsum(const float* __restrict__ x, const int* __restrict__ batch,
                           float* __restrict__ g) {
  int t = threadIdx.x;  // 128 dims
  int n0 = blockIdx.x * GS_NODES;
  int nend = n0 + GS_NODES;
  if (nend > NN) nend = NN;
  if (n0 >= NN) return;
  float acc = 0.f;
  int cur = batch[n0];
  for (int n = n0; n < nend; ++n) {
    int bb = batch[n];
    if (bb != cur) {
      atomicAdd(&g[(size_t)cur * DDIM + t], acc);
      acc = 0.f;
      cur = bb;
    }
    acc += x[(size_t)n * DDIM + t];
  }
  atomicAdd(&g[(size_t)cur * DDIM + t], acc);
}

// ---------------- output projection ----------------

__global__ void k_out(const float* __restrict__ g, const float* __restrict__ W,
                      const float* __restrict__ b, float* __restrict__ out) {
  int idx = blockIdx.x * blockDim.x + threadIdx.x;
  if (idx >= NGRAPH * DOUT) return;
  int r = idx / DOUT, c = idx % DOUT;
  float acc = b[c];
#pragma unroll 8
  for (int k = 0; k < DDIM; ++k) acc = fmaf(g[r * DDIM + k], W[k * DOUT + c], acc);
  out[idx] = acc;
}

// ---------------- launch ----------------

extern "C" void kernel_launch(void* const* d_in, const int* in_sizes, int n_in,
                              void* d_out, int out_size, void* d_ws, size_t ws_size,
                              hipStream_t stream) {
  const float* pos = (const float*)d_in[0];
  const int* at = (const int*)d_in[1];
  const int* ei = (const int*)d_in[2];
  const int* batch = (const int*)d_in[3];
  const float* emb = (const float*)d_in[4];
  const float* W_init = (const float*)d_in[5];
  const float* b_init = (const float*)d_in[6];
  const float* Wq = (const float*)d_in[7];
  const float* Wk = (const float*)d_in[8];
  const float* Wv = (const float*)d_in[9];
  const float* We = (const float*)d_in[10];
  const float* Wo = (const float*)d_in[11];
  const float* Wm1 = (const float*)d_in[12];
  const float* bm1 = (const float*)d_in[13];
  const float* Wm2 = (const float*)d_in[14];
  const float* bm2 = (const float*)d_in[15];
  const float* ln_g = (const float*)d_in[16];
  const float* ln_b = (const float*)d_in[17];
  const float* W_out = (const float*)d_in[18];
  const float* b_out = (const float*)d_in[19];
  float* out = (float*)d_out;

  const size_t ND = (size_t)NN * DDIM;  // 6.4M
  float* x = (float*)d_ws;              // f32 ND
  ushort* qnb = (ushort*)(x + ND);      // bf16 ND
  ushort* knb = qnb + ND;               // bf16 ND
  ushort* vnb = knb + ND;               // bf16 ND
  ushort* msgb = vnb + ND;              // bf16 ND
  ushort* qe = msgb + ND;               // bf16 NN*200
  ushort* Wtb = qe + (size_t)NN * 200;  // bf16 12*16384
  float* de = (float*)(Wtb + 12 * 16384);  // f32 NE
  int* deg = (int*)(de + NE);
  int* cnear = deg + NN;
  int* cfar = cnear + NN;
  int* rowptr = cfar + NN;
  int2* er = (int2*)(rowptr + NN + 64);  // NE int2
  float* gb = (float*)(er + NE);         // NG*DDIM
  int* bsum = (int*)(gb + NGRAPH * DDIM);  // SCAN_N
  // total ~96 MB

  k_wconv<<<12 * 16384 / 256, 256, 0, stream>>>(Wq, Wk, Wv, Wo, Wm1, Wm2, Wtb);
  k_fill_i<<<(NN + 255) / 256, 256, 0, stream>>>(deg, 0, NN);
  k_init<<<(NN * DDIM + 255) / 256, 256, 0, stream>>>(pos, at, emb, W_init, b_init, x);
  k_edge<<<(NE + 255) / 256, 256, 0, stream>>>(pos, ei, de, deg);
  k_scan1<<<SCAN_N, 256, 0, stream>>>(deg, bsum);
  k_scan2<<<1, 256, 0, stream>>>(bsum);
  k_scan3<<<SCAN_N, 256, 0, stream>>>(deg, bsum, rowptr, cnear, cfar);
  k_scatter<<<(NE + 255) / 256, 256, 0, stream>>>(ei, de, cnear, cfar, er);

  const int gg = (NN + 127) / 128;  // 391
  for (int l = 0; l < 2; ++l) {
    const ushort* Wt_l = Wtb + (size_t)l * 6 * 16384;
    const float* We_l = We + (size_t)l * NRAD * DDIM;

    k_qkv<<<gg, 256, 0, stream>>>(x, Wt_l, qnb, knb, vnb);
    k_qe<<<NN / 8, 256, 0, stream>>>(qnb, We_l, qe);
    k_attn4<<<NN / 4, 256, 0, stream>>>(qnb, knb, vnb, qe, er, rowptr, cnear, We_l, msgb);

    // megafused: x += msg@Wo; LN; gelu(@Wm1+bm1); x += @Wm2+bm2
    k_fc<<<gg, 256, 0, stream>>>(msgb, Wt_l + 3 * 16384, x,
                                 ln_g + (size_t)l * DDIM, ln_b + (size_t)l * DDIM,
                                 bm1 + (size_t)l * DDIM, bm2 + (size_t)l * DDIM);
  }

  k_fill_f<<<(NGRAPH * DDIM + 255) / 256, 256, 0, stream>>>(gb, 0.f, NGRAPH * DDIM);
  k_graphsum<<<(NN + GS_NODES - 1) / GS_NODES, 128, 0, stream>>>(x, batch, gb);
  k_out<<<(NGRAPH * DOUT + 255) / 256, 256, 0, stream>>>(gb, W_out, b_out, out);
}

// Round 9
// 493.153 us; speedup vs baseline: 1.0565x; 1.0565x over previous
//
#include <hip/hip_runtime.h>
#include <math.h>

#define NN 50000
#define NE 400000
#define DDIM 128
#define NHEAD 4
#define NRAD 50
#define NGRAPH 100
#define TEMB 32
#define DOUT 512
#define CUTF 6.0f
#define PI_F 3.14159265358979323846f

#define SCAN_N ((NN + 255) / 256)  // 196 scan blocks

typedef unsigned int uint;
typedef unsigned short ushort;
typedef __attribute__((ext_vector_type(8))) short short8;
typedef __attribute__((ext_vector_type(4))) float f32x4;

// ---------------- helpers ----------------

__device__ __forceinline__ float gelu_tanh(float v) {
  float u = 0.7978845608028654f * (v + 0.044715f * v * v * v);
  return 0.5f * v * (1.0f + tanhf(u));
}

__device__ __forceinline__ ushort f2bf(float f) {  // RNE
  uint u = __float_as_uint(f);
  uint r = (u + 0x7fffu + ((u >> 16) & 1u)) >> 16;
  return (ushort)r;
}
__device__ __forceinline__ float bfl(uint u) { return __uint_as_float(u << 16); }
__device__ __forceinline__ float bfh(uint u) { return __uint_as_float(u & 0xffff0000u); }

// 16-lane sum reduction entirely on the VALU via DPP (no ds_bpermute).
// Steps: quad xor1 (0xB1), quad xor2 (0x4E), half-mirror (0x141), mirror (0x140).
__device__ __forceinline__ float red16(float v) {
  v += __int_as_float(__builtin_amdgcn_update_dpp(0, __float_as_int(v), 0xB1, 0xF, 0xF, true));
  v += __int_as_float(__builtin_amdgcn_update_dpp(0, __float_as_int(v), 0x4E, 0xF, 0xF, true));
  v += __int_as_float(__builtin_amdgcn_update_dpp(0, __float_as_int(v), 0x141, 0xF, 0xF, true));
  v += __int_as_float(__builtin_amdgcn_update_dpp(0, __float_as_int(v), 0x140, 0xF, 0xF, true));
  return v;
}

__global__ void k_fill_f(float* p, float v, int n) {
  int i = blockIdx.x * blockDim.x + threadIdx.x;
  if (i < n) p[i] = v;
}
__global__ void k_fill_i(int* p, int v, int n) {
  int i = blockIdx.x * blockDim.x + threadIdx.x;
  if (i < n) p[i] = v;
}

// ---------------- weight pre-convert + transpose: Wtb[l][fam][c][k] bf16 ----------------

__global__ void k_wconv(const float* __restrict__ Wq, const float* __restrict__ Wk,
                        const float* __restrict__ Wv, const float* __restrict__ Wo,
                        const float* __restrict__ Wm1, const float* __restrict__ Wm2,
                        ushort* __restrict__ Wtb) {
  int idx = blockIdx.x * 256 + threadIdx.x;  // 12*16384
  int m = idx >> 14;
  int r = idx & 16383;
  int c = r >> 7, k = r & 127;
  int l = m / 6, fam = m % 6;
  const float* src = fam == 0 ? Wq : fam == 1 ? Wk : fam == 2 ? Wv
                   : fam == 3 ? Wo : fam == 4 ? Wm1 : Wm2;
  Wtb[idx] = f2bf(src[l * 16384 + k * 128 + c]);
}

// ---------------- init: x = [emb[at], pos] @ W_init + b ----------------

__global__ void k_init(const float* __restrict__ pos, const int* __restrict__ at,
                       const float* __restrict__ emb, const float* __restrict__ W,
                       const float* __restrict__ b, float* __restrict__ x) {
  int idx = blockIdx.x * blockDim.x + threadIdx.x;
  if (idx >= NN * DDIM) return;
  int n = idx >> 7, c = idx & 127;
  const float* er = emb + (size_t)at[n] * TEMB;
  float acc = b[c];
#pragma unroll
  for (int t = 0; t < TEMB; ++t) acc = fmaf(er[t], W[t * DDIM + c], acc);
  acc = fmaf(pos[n * 3 + 0], W[(TEMB + 0) * DDIM + c], acc);
  acc = fmaf(pos[n * 3 + 1], W[(TEMB + 1) * DDIM + c], acc);
  acc = fmaf(pos[n * 3 + 2], W[(TEMB + 2) * DDIM + c], acc);
  x[idx] = acc;
}

// ---------------- per-edge distance + degree histogram (fused) ----------------

__global__ void k_edge(const float* __restrict__ pos, const int* __restrict__ ei,
                       float* __restrict__ de, int* __restrict__ deg) {
  int e = blockIdx.x * blockDim.x + threadIdx.x;
  if (e >= NE) return;
  int s = ei[e], t = ei[NE + e];
  float dx = pos[s * 3 + 0] - pos[t * 3 + 0] + 1e-8f;
  float dy = pos[s * 3 + 1] - pos[t * 3 + 1] + 1e-8f;
  float dz = pos[s * 3 + 2] - pos[t * 3 + 2] + 1e-8f;
  de[e] = sqrtf(dx * dx + dy * dy + dz * dz);
  atomicAdd(&deg[t], 1);
}

// ---------------- CSR build: parallel 3-pass exclusive scan ----------------

__global__ void k_scan1(const int* __restrict__ deg, int* __restrict__ bsum) {
  __shared__ int red[256];
  int i = blockIdx.x * 256 + threadIdx.x;
  red[threadIdx.x] = (i < NN) ? deg[i] : 0;
  __syncthreads();
  for (int off = 128; off > 0; off >>= 1) {
    if (threadIdx.x < off) red[threadIdx.x] += red[threadIdx.x + off];
    __syncthreads();
  }
  if (threadIdx.x == 0) bsum[blockIdx.x] = red[0];
}

__global__ void k_scan2(int* __restrict__ bsum) {  // 1 block, 256 threads >= SCAN_N
  __shared__ int sh[256];
  int t = threadIdx.x;
  int v = (t < SCAN_N) ? bsum[t] : 0;
  sh[t] = v;
  __syncthreads();
  for (int off = 1; off < 256; off <<= 1) {
    int u = (t >= off) ? sh[t - off] : 0;
    __syncthreads();
    sh[t] += u;
    __syncthreads();
  }
  if (t < SCAN_N) bsum[t] = (t == 0) ? 0 : sh[t - 1];
}

__global__ void k_scan3(const int* __restrict__ deg, const int* __restrict__ bsum,
                        int* __restrict__ rowptr, int* __restrict__ cnear,
                        int* __restrict__ cfar) {
  __shared__ int sh[256];
  int t = threadIdx.x;
  int i = blockIdx.x * 256 + t;
  int v = (i < NN) ? deg[i] : 0;
  sh[t] = v;
  __syncthreads();
  for (int off = 1; off < 256; off <<= 1) {
    int u = (t >= off) ? sh[t - off] : 0;
    __syncthreads();
    sh[t] += u;
    __syncthreads();
  }
  int excl = bsum[blockIdx.x] + sh[t] - v;
  if (i < NN) {
    rowptr[i] = excl;
    cnear[i] = excl;
    cfar[i] = excl + v;  // = rowptr[i+1]
    if (i == NN - 1) rowptr[NN] = excl + v;
  }
}

// scatter into near-first / far-last segmented CSR, packed records {src, d}
__global__ void k_scatter(const int* __restrict__ ei, const float* __restrict__ de,
                          int* __restrict__ cnear, int* __restrict__ cfar,
                          int2* __restrict__ er) {
  int e = blockIdx.x * blockDim.x + threadIdx.x;
  if (e >= NE) return;
  int src = ei[e], dst = ei[NE + e];
  float d = de[e];
  int idx;
  if (d < CUTF)
    idx = atomicAdd(&cnear[dst], 1);
  else
    idx = atomicSub(&cfar[dst], 1) - 1;
  er[idx] = make_int2(src, __float_as_int(d));
}

// ---------------- fused QKV GEMM: stage x once, 3 weights ----------------
// block 256 = 4 waves; 128 rows x 128 cols; 16x16x32 bf16 MFMA; wave owns 32 rows.

__global__ __launch_bounds__(256) void k_qkv(
    const float* __restrict__ x, const ushort* __restrict__ Wt3,
    ushort* __restrict__ qo, ushort* __restrict__ ko, ushort* __restrict__ vo) {
  __shared__ ushort Al[128 * 128];
  __shared__ ushort Wl[128 * 128];
  const int tid = threadIdx.x;
  const int r0 = blockIdx.x * 128;

  for (int i = tid; i < 128 * 16; i += 256) {
    int r = i >> 4, g = i & 15;
    int gr = r0 + r;
    float4 f0 = {0, 0, 0, 0}, f1 = {0, 0, 0, 0};
    if (gr < NN) {
      f0 = *(const float4*)&x[(size_t)gr * 128 + g * 8];
      f1 = *(const float4*)&x[(size_t)gr * 128 + g * 8 + 4];
    }
    int gs = g ^ (r & 7);
    ushort4 u0 = {f2bf(f0.x), f2bf(f0.y), f2bf(f0.z), f2bf(f0.w)};
    ushort4 u1 = {f2bf(f1.x), f2bf(f1.y), f2bf(f1.z), f2bf(f1.w)};
    *(ushort4*)&Al[r * 128 + gs * 8] = u0;
    *(ushort4*)&Al[r * 128 + gs * 8 + 4] = u1;
  }

  const int w = tid >> 6, l = tid & 63;
  const int lg = l >> 4, lr = l & 15;

  for (int m = 0; m < 3; ++m) {
    for (int i = tid; i < 128 * 16; i += 256) {
      int c = i >> 4, g = i & 15;
      ushort4 w0 = *(const ushort4*)&Wt3[m * 16384 + c * 128 + g * 8];
      ushort4 w1 = *(const ushort4*)&Wt3[m * 16384 + c * 128 + g * 8 + 4];
      int gs = g ^ (c & 7);
      *(ushort4*)&Wl[c * 128 + gs * 8] = w0;
      *(ushort4*)&Wl[c * 128 + gs * 8 + 4] = w1;
    }
    __syncthreads();

    f32x4 acc[2][8];
#pragma unroll
    for (int rt = 0; rt < 2; ++rt)
#pragma unroll
      for (int ct = 0; ct < 8; ++ct) acc[rt][ct] = (f32x4){0.f, 0.f, 0.f, 0.f};

#pragma unroll
    for (int ks = 0; ks < 4; ++ks) {
      short8 af[2];
#pragma unroll
      for (int rt = 0; rt < 2; ++rt) {
        int arow = w * 32 + rt * 16 + lr;
        int ga = (ks * 4 + lg) ^ (arow & 7);
        af[rt] = *(const short8*)&Al[arow * 128 + ga * 8];
      }
#pragma unroll
      for (int ct = 0; ct < 8; ++ct) {
        int col = ct * 16 + lr;
        int gb = (ks * 4 + lg) ^ (col & 7);
        short8 bf = *(const short8*)&Wl[col * 128 + gb * 8];
#pragma unroll
        for (int rt = 0; rt < 2; ++rt)
          acc[rt][ct] = __builtin_amdgcn_mfma_f32_16x16x32_bf16(af[rt], bf, acc[rt][ct], 0, 0, 0);
      }
    }

    ushort* o = (m == 0) ? qo : (m == 1) ? ko : vo;
#pragma unroll
    for (int rt = 0; rt < 2; ++rt)
#pragma unroll
      for (int ct = 0; ct < 8; ++ct) {
        int col = ct * 16 + lr;
#pragma unroll
        for (int r = 0; r < 4; ++r) {
          int row = r0 + w * 32 + rt * 16 + lg * 4 + r;
          if (row < NN) o[(size_t)row * 128 + col] = f2bf(acc[rt][ct][r]);
        }
      }
    __syncthreads();
  }
}

// ---------------- general GEMM: out = act(A@W + bias) (+resid) (+fused LN), A bf16 ----------------

template <bool BIAS, bool GELU, bool RESID, bool LNF>
__global__ __launch_bounds__(256) void k_gemm2(
    const ushort* __restrict__ A, const ushort* __restrict__ Wt,
    const float* __restrict__ bias, const float* __restrict__ resid,
    void* __restrict__ outp, const float* __restrict__ lng,
    const float* __restrict__ lnb, ushort* __restrict__ lnout) {
  __shared__ ushort Al[128 * 128];
  __shared__ ushort Wl[128 * 128];
  const int tid = threadIdx.x;
  const int r0 = blockIdx.x * 128;

  for (int i = tid; i < 128 * 16; i += 256) {
    int r = i >> 4, g = i & 15;
    int gr = r0 + r;
    ushort4 v0 = {0, 0, 0, 0}, v1 = {0, 0, 0, 0};
    if (gr < NN) {
      v0 = *(const ushort4*)&A[(size_t)gr * 128 + g * 8];
      v1 = *(const ushort4*)&A[(size_t)gr * 128 + g * 8 + 4];
    }
    int gs = g ^ (r & 7);
    *(ushort4*)&Al[r * 128 + gs * 8] = v0;
    *(ushort4*)&Al[r * 128 + gs * 8 + 4] = v1;
  }
  for (int i = tid; i < 128 * 16; i += 256) {
    int c = i >> 4, g = i & 15;
    ushort4 w0 = *(const ushort4*)&Wt[c * 128 + g * 8];
    ushort4 w1 = *(const ushort4*)&Wt[c * 128 + g * 8 + 4];
    int gs = g ^ (c & 7);
    *(ushort4*)&Wl[c * 128 + gs * 8] = w0;
    *(ushort4*)&Wl[c * 128 + gs * 8 + 4] = w1;
  }
  __syncthreads();

  const int w = tid >> 6, l = tid & 63;
  const int lg = l >> 4, lr = l & 15;
  f32x4 acc[2][8];
#pragma unroll
  for (int rt = 0; rt < 2; ++rt)
#pragma unroll
    for (int ct = 0; ct < 8; ++ct) acc[rt][ct] = (f32x4){0.f, 0.f, 0.f, 0.f};

#pragma unroll
  for (int ks = 0; ks < 4; ++ks) {
    short8 af[2];
#pragma unroll
    for (int rt = 0; rt < 2; ++rt) {
      int arow = w * 32 + rt * 16 + lr;
      int ga = (ks * 4 + lg) ^ (arow & 7);
      af[rt] = *(const short8*)&Al[arow * 128 + ga * 8];
    }
#pragma unroll
    for (int ct = 0; ct < 8; ++ct) {
      int col = ct * 16 + lr;
      int gb = (ks * 4 + lg) ^ (col & 7);
      short8 bf = *(const short8*)&Wl[col * 128 + gb * 8];
#pragma unroll
      for (int rt = 0; rt < 2; ++rt)
        acc[rt][ct] = __builtin_amdgcn_mfma_f32_16x16x32_bf16(af[rt], bf, acc[rt][ct], 0, 0, 0);
    }
  }

#pragma unroll
  for (int rt = 0; rt < 2; ++rt)
#pragma unroll
    for (int r = 0; r < 4; ++r) {
      int row = r0 + w * 32 + rt * 16 + lg * 4 + r;
      bool ok = row < NN;  // uniform across the 16-lane lr group
      float v[8];
#pragma unroll
      for (int ct = 0; ct < 8; ++ct) {
        int col = ct * 16 + lr;
        float vv = acc[rt][ct][r];
        if (BIAS) vv += bias[col];
        if (GELU) vv = gelu_tanh(vv);
        if (RESID) vv += ok ? resid[(size_t)row * 128 + col] : 0.f;
        v[ct] = vv;
      }
      if (RESID || LNF) {
        if (ok)
#pragma unroll
          for (int ct = 0; ct < 8; ++ct)
            ((float*)outp)[(size_t)row * 128 + ct * 16 + lr] = v[ct];
      } else {
        if (ok)
#pragma unroll
          for (int ct = 0; ct < 8; ++ct)
            ((ushort*)outp)[(size_t)row * 128 + ct * 16 + lr] = f2bf(v[ct]);
      }
      if (LNF) {
        float s = 0.f, ss = 0.f;
#pragma unroll
        for (int ct = 0; ct < 8; ++ct) {
          s += v[ct];
          ss = fmaf(v[ct], v[ct], ss);
        }
#pragma unroll
        for (int msk = 8; msk >= 1; msk >>= 1) {
          s += __shfl_xor(s, msk);
          ss += __shfl_xor(ss, msk);
        }
        float mean = s * (1.0f / DDIM);
        float var = ss * (1.0f / DDIM) - mean * mean;
        float inv = rsqrtf(var + 1e-5f);
        if (ok)
#pragma unroll
          for (int ct = 0; ct < 8; ++ct) {
            int col = ct * 16 + lr;
            lnout[(size_t)row * 128 + col] =
                f2bf((v[ct] - mean) * inv * lng[col] + lnb[col]);
          }
      }
    }
}

// ---------------- qe precompute: qe[n][j][h] ----------------

__global__ __launch_bounds__(256) void k_qe(const ushort* __restrict__ qnb,
                                            const float* __restrict__ We,
                                            ushort* __restrict__ qe) {
  __shared__ float Wlds[NRAD][DDIM + 1];
  __shared__ float qlds[4][DDIM];
  int tid = threadIdx.x;
  for (int i = tid; i < NRAD * DDIM; i += 256) Wlds[i / DDIM][i % DDIM] = We[i];
  __syncthreads();
  int w = tid >> 6, t = tid & 63;
  for (int rep = 0; rep < 2; ++rep) {
    int n = blockIdx.x * 8 + rep * 4 + w;
    uint qu = *(const uint*)&qnb[(size_t)n * DDIM + 2 * t];
    qlds[w][2 * t] = bfl(qu);
    qlds[w][2 * t + 1] = bfh(qu);
    if (t < NRAD) {
      float e0 = 0.f, e1 = 0.f, e2 = 0.f, e3 = 0.f;
#pragma unroll
      for (int d = 0; d < 32; ++d) e0 = fmaf(Wlds[t][d], qlds[w][d], e0);
#pragma unroll
      for (int d = 32; d < 64; ++d) e1 = fmaf(Wlds[t][d], qlds[w][d], e1);
#pragma unroll
      for (int d = 64; d < 96; ++d) e2 = fmaf(Wlds[t][d], qlds[w][d], e2);
#pragma unroll
      for (int d = 96; d < 128; ++d) e3 = fmaf(Wlds[t][d], qlds[w][d], e3);
      ushort4 o = {f2bf(e0), f2bf(e1), f2bf(e2), f2bf(e3)};
      *(ushort4*)&qe[(size_t)n * (NRAD * 4) + 4 * t] = o;
    }
  }
}

// ---------------- fused attention v5: near/far split CSR, DPP butterfly softmax ----------------

__device__ __forceinline__ float rbf_fill(float d, int j) {
  const float step = CUTF / (NRAD - 1);
  const float gamma = (NRAD / CUTF) * (NRAD / CUTF);
  float mu = j * step;
  float dm = d - mu;
  float env = 0.5f * (__cosf(PI_F * d / CUTF) + 1.0f);
  return __expf(-gamma * dm * dm) * env;
}

#define SCALE_QK 0.17677669529663687f

__global__ __launch_bounds__(256) void k_attn5(
    const ushort* __restrict__ qnb, const ushort* __restrict__ knb,
    const ushort* __restrict__ vnb, const ushort* __restrict__ qe,
    const int2* __restrict__ er, const int* __restrict__ rowptr,
    const int* __restrict__ nearend, const float* __restrict__ We,
    ushort* __restrict__ msgb) {
  __shared__ float qel[4][64][4];   // [wave][j][head]; reused for arbn in epilogue
  __shared__ float rbl[4][64];
  __shared__ ushort Wel[NRAD * DDIM];
  const int tid = threadIdx.x;
  for (int i = tid; i < NRAD * DDIM; i += 256) Wel[i] = f2bf(We[i]);
  __syncthreads();

  const int w = tid >> 6, t = tid & 63;
  const int n = blockIdx.x * 4 + w;
  const int h = t >> 4;
  const int j0 = t & 15;
  uint qu = *(const uint*)&qnb[(size_t)n * DDIM + 2 * t];
  const float q0 = bfl(qu), q1 = bfh(qu);
  if (t < NRAD) {
    ushort4 qv = *(const ushort4*)&qe[(size_t)n * (NRAD * 4) + 4 * t];
    qel[w][t][0] = bfl(qv.x);
    qel[w][t][1] = bfl(qv.y);
    qel[w][t][2] = bfl(qv.z);
    qel[w][t][3] = bfl(qv.w);
  } else {
    qel[w][t][0] = 0.f; qel[w][t][1] = 0.f; qel[w][t][2] = 0.f; qel[w][t][3] = 0.f;
  }
  const int start = rowptr[n], nend = nearend[n], end = rowptr[n + 1];

  float s = 0.f, a0 = 0.f, a1 = 0.f;
  float4 arb = {0.f, 0.f, 0.f, 0.f};

  // ---- near loop (radial features active) ----
  for (int cb = start; cb < nend; cb += 64) {
    int cnt = min(nend - cb, 64);
    int2 e_t = make_int2(0, 0);
    if (t < cnt) e_t = er[cb + t];
    for (int i = 0; i < cnt; ++i) {
      int src = __shfl(e_t.x, i);
      float dd = __shfl(__int_as_float(e_t.y), i);
      uint ku = *(const uint*)&knb[(size_t)src * DDIM + 2 * t];
      uint vu = *(const uint*)&vnb[(size_t)src * DDIM + 2 * t];
      float pr = q0 * bfl(ku) + q1 * bfh(ku);
      float rb = (t < NRAD) ? rbf_fill(dd, t) : 0.f;
      rbl[w][t] = rb;
      pr = fmaf(rbl[w][j0], qel[w][j0][h], pr);
      pr = fmaf(rbl[w][j0 + 16], qel[w][j0 + 16][h], pr);
      pr = fmaf(rbl[w][j0 + 32], qel[w][j0 + 32][h], pr);
      pr = fmaf(rbl[w][j0 + 48], qel[w][j0 + 48][h], pr);
      pr = red16(pr);
      float ae = __expf(fminf(pr * SCALE_QK, 60.f));
      s += ae;
      a0 = fmaf(ae, bfl(vu), a0);
      a1 = fmaf(ae, bfh(vu), a1);
      float aex = __shfl(ae, 0);
      float aey = __shfl(ae, 16);
      float aez = __shfl(ae, 32);
      float aew = __shfl(ae, 48);
      arb.x = fmaf(rb, aex, arb.x);
      arb.y = fmaf(rb, aey, arb.y);
      arb.z = fmaf(rb, aez, arb.z);
      arb.w = fmaf(rb, aew, arb.w);
    }
  }

  // ---- far loop (no radial), 2-edge unrolled for ILP ----
  float s1 = 0.f, b0 = 0.f, b1 = 0.f;
  for (int cb = nend; cb < end; cb += 64) {
    int cnt = min(end - cb, 64);
    int src_t = 0;
    if (t < cnt) src_t = er[cb + t].x;
    int i = 0;
    for (; i + 2 <= cnt; i += 2) {
      int sA = __shfl(src_t, i);
      int sB = __shfl(src_t, i + 1);
      uint kuA = *(const uint*)&knb[(size_t)sA * DDIM + 2 * t];
      uint kuB = *(const uint*)&knb[(size_t)sB * DDIM + 2 * t];
      uint vuA = *(const uint*)&vnb[(size_t)sA * DDIM + 2 * t];
      uint vuB = *(const uint*)&vnb[(size_t)sB * DDIM + 2 * t];
      float pA = q0 * bfl(kuA) + q1 * bfh(kuA);
      float pB = q0 * bfl(kuB) + q1 * bfh(kuB);
      pA = red16(pA);
      pB = red16(pB);
      float aeA = __expf(fminf(pA * SCALE_QK, 60.f));
      float aeB = __expf(fminf(pB * SCALE_QK, 60.f));
      s += aeA;
      s1 += aeB;
      a0 = fmaf(aeA, bfl(vuA), a0);
      b0 = fmaf(aeB, bfl(vuB), b0);
      a1 = fmaf(aeA, bfh(vuA), a1);
      b1 = fmaf(aeB, bfh(vuB), b1);
    }
    if (i < cnt) {
      int sA = __shfl(src_t, i);
      uint kuA = *(const uint*)&knb[(size_t)sA * DDIM + 2 * t];
      uint vuA = *(const uint*)&vnb[(size_t)sA * DDIM + 2 * t];
      float pA = q0 * bfl(kuA) + q1 * bfh(kuA);
      pA = red16(pA);
      float aeA = __expf(fminf(pA * SCALE_QK, 60.f));
      s += aeA;
      a0 = fmaf(aeA, bfl(vuA), a0);
      a1 = fmaf(aeA, bfh(vuA), a1);
    }
  }
  s += s1;
  a0 += b0;
  a1 += b1;

  // ---- finalize: normalize; msg = a_norm + (arb_norm @ We) ----
  float4 s4 = {__shfl(s, 0), __shfl(s, 16), __shfl(s, 32), __shfl(s, 48)};
  float4 inv4 = {1.f / (s4.x + 1e-9f), 1.f / (s4.y + 1e-9f),
                 1.f / (s4.z + 1e-9f), 1.f / (s4.w + 1e-9f)};
  float invo = 1.f / (s + 1e-9f);
  if (t < NRAD) {
    qel[w][t][0] = arb.x * inv4.x;
    qel[w][t][1] = arb.y * inv4.y;
    qel[w][t][2] = arb.z * inv4.z;
    qel[w][t][3] = arb.w * inv4.w;
  }
  a0 *= invo;
  a1 *= invo;
#pragma unroll 10
  for (int j = 0; j < NRAD; ++j) {
    float ar = qel[w][j][h];
    uint wu = *(const uint*)&Wel[j * DDIM + 2 * t];
    a0 = fmaf(ar, bfl(wu), a0);
    a1 = fmaf(ar, bfh(wu), a1);
  }
  uint pk = (uint)f2bf(a0) | ((uint)f2bf(a1) << 16);
  *(uint*)&msgb[(size_t)n * DDIM + 2 * t] = pk;
}

// ---------------- graph sum (batch is sorted): 32 nodes/block, boundary atomics ----------------

#define GS_NODES 32
__global__ void k_graphsum(const float* __restrict__ x, const int* __restrict__ batch,
                           float* __restrict__ g) {
  int t = threadIdx.x;  // 128 dims
  int n0 = blockIdx.x * GS_NODES;
  int nend = n0 + GS_NODES;
  if (nend > NN) nend = NN;
  if (n0 >= NN) return;
  float acc = 0.f;
  int cur = batch[n0];
  for (int n = n0; n < nend; ++n) {
    int bb = batch[n];
    if (bb != cur) {
      atomicAdd(&g[(size_t)cur * DDIM + t], acc);
      acc = 0.f;
      cur = bb;
    }
    acc += x[(size_t)n * DDIM + t];
  }
  atomicAdd(&g[(size_t)cur * DDIM + t], acc);
}

// ---------------- output projection ----------------

__global__ void k_out(const float* __restrict__ g, const float* __restrict__ W,
                      const float* __restrict__ b, float* __restrict__ out) {
  int idx = blockIdx.x * blockDim.x + threadIdx.x;
  if (idx >= NGRAPH * DOUT) return;
  int r = idx / DOUT, c = idx % DOUT;
  float acc = b[c];
#pragma unroll 8
  for (int k = 0; k < DDIM; ++k) acc = fmaf(g[r * DDIM + k], W[k * DOUT + c], acc);
  out[idx] = acc;
}

// ---------------- launch ----------------

extern "C" void kernel_launch(void* const* d_in, const int* in_sizes, int n_in,
                              void* d_out, int out_size, void* d_ws, size_t ws_size,
                              hipStream_t stream) {
  const float* pos = (const float*)d_in[0];
  const int* at = (const int*)d_in[1];
  const int* ei = (const int*)d_in[2];
  const int* batch = (const int*)d_in[3];
  const float* emb = (const float*)d_in[4];
  const float* W_init = (const float*)d_in[5];
  const float* b_init = (const float*)d_in[6];
  const float* Wq = (const float*)d_in[7];
  const float* Wk = (const float*)d_in[8];
  const float* Wv = (const float*)d_in[9];
  const float* We = (const float*)d_in[10];
  const float* Wo = (const float*)d_in[11];
  const float* Wm1 = (const float*)d_in[12];
  const float* bm1 = (const float*)d_in[13];
  const float* Wm2 = (const float*)d_in[14];
  const float* bm2 = (const float*)d_in[15];
  const float* ln_g = (const float*)d_in[16];
  const float* ln_b = (const float*)d_in[17];
  const float* W_out = (const float*)d_in[18];
  const float* b_out = (const float*)d_in[19];
  float* out = (float*)d_out;

  const size_t ND = (size_t)NN * DDIM;  // 6.4M
  float* x = (float*)d_ws;              // f32 ND
  ushort* qnb = (ushort*)(x + ND);      // bf16 ND (alias hb)
  ushort* knb = qnb + ND;               // bf16 ND (alias h2)
  ushort* vnb = knb + ND;               // bf16 ND
  ushort* msgb = vnb + ND;              // bf16 ND
  ushort* qe = msgb + ND;               // bf16 NN*200
  ushort* Wtb = qe + (size_t)NN * 200;  // bf16 12*16384
  float* de = (float*)(Wtb + 12 * 16384);  // f32 NE
  int* deg = (int*)(de + NE);
  int* cnear = deg + NN;
  int* cfar = cnear + NN;
  int* rowptr = cfar + NN;
  int2* er = (int2*)(rowptr + NN + 64);  // NE int2
  float* gb = (float*)(er + NE);         // NG*DDIM
  int* bsum = (int*)(gb + NGRAPH * DDIM);  // SCAN_N
  // total ~96 MB

  ushort* hb = qnb;
  ushort* h2 = knb;

  k_wconv<<<12 * 16384 / 256, 256, 0, stream>>>(Wq, Wk, Wv, Wo, Wm1, Wm2, Wtb);
  k_fill_i<<<(NN + 255) / 256, 256, 0, stream>>>(deg, 0, NN);
  k_init<<<(NN * DDIM + 255) / 256, 256, 0, stream>>>(pos, at, emb, W_init, b_init, x);
  k_edge<<<(NE + 255) / 256, 256, 0, stream>>>(pos, ei, de, deg);
  k_scan1<<<SCAN_N, 256, 0, stream>>>(deg, bsum);
  k_scan2<<<1, 256, 0, stream>>>(bsum);
  k_scan3<<<SCAN_N, 256, 0, stream>>>(deg, bsum, rowptr, cnear, cfar);
  k_scatter<<<(NE + 255) / 256, 256, 0, stream>>>(ei, de, cnear, cfar, er);

  const int gg = (NN + 127) / 128;  // 391
  for (int l = 0; l < 2; ++l) {
    const ushort* Wt_l = Wtb + (size_t)l * 6 * 16384;
    const float* We_l = We + (size_t)l * NRAD * DDIM;

    k_qkv<<<gg, 256, 0, stream>>>(x, Wt_l, qnb, knb, vnb);
    k_qe<<<NN / 8, 256, 0, stream>>>(qnb, We_l, qe);
    k_attn5<<<NN / 4, 256, 0, stream>>>(qnb, knb, vnb, qe, er, rowptr, cnear, We_l, msgb);

    // x += msg@Wo, fused layernorm -> hb
    k_gemm2<false, false, true, true><<<gg, 256, 0, stream>>>(
        msgb, Wt_l + 3 * 16384, nullptr, x, x,
        ln_g + (size_t)l * DDIM, ln_b + (size_t)l * DDIM, hb);
    // h2 = gelu(hb@Wm1 + bm1)
    k_gemm2<true, true, false, false><<<gg, 256, 0, stream>>>(
        hb, Wt_l + 4 * 16384, bm1 + (size_t)l * DDIM, nullptr, h2, nullptr, nullptr, nullptr);
    // x += h2@Wm2 + bm2
    k_gemm2<true, false, true, false><<<gg, 256, 0, stream>>>(
        h2, Wt_l + 5 * 16384, bm2 + (size_t)l * DDIM, x, x, nullptr, nullptr, nullptr);
  }

  k_fill_f<<<(NGRAPH * DDIM + 255) / 256, 256, 0, stream>>>(gb, 0.f, NGRAPH * DDIM);
  k_graphsum<<<(NN + GS_NODES - 1) / GS_NODES, 128, 0, stream>>>(x, batch, gb);
  k_out<<<(NGRAPH * DOUT + 255) / 256, 256, 0, stream>>>(gb, W_out, b_out, out);
}